// Round 1
// baseline (460.220 us; speedup 1.0000x reference)
//
#include <hip/hip_runtime.h>

// Problem constants (match the JAX reference).
#define B_   32
#define S_   4096
#define F_   512
#define K_   25
#define F4_  (F_ / 4)          // 128 float4 columns per row
#define SEG  100               // s-segment per thread; MUST be a multiple of K_
#define NSEG ((S_ + SEG - 1) / SEG)   // 41 (last segment partially masked)

// Causal K=25 sliding-window filter along S, edge-clamped at s=0.
// One thread per (b, segment, float4-f-column). 25-entry float4 circular
// window lives in registers; the s-loop is unrolled by 25 so every window
// index is a compile-time constant (slot = s % 25 == u).
__global__ __launch_bounds__(256, 2)
void adapt_smoothing_kernel(const float* __restrict__ x,
                            const float* __restrict__ w,
                            float* __restrict__ out) {
    const int tid  = blockIdx.x * blockDim.x + threadIdx.x;
    const int f4   = tid & (F4_ - 1);
    const int rest = tid >> 7;              // / F4_
    if (rest >= B_ * NSEG) return;
    const int seg = rest % NSEG;
    const int b   = rest / NSEG;
    const int s0  = seg * SEG;              // s0 % 25 == 0

    // Weights: wave-uniform address -> scalar loads -> SGPRs.
    float wt[K_];
#pragma unroll
    for (int l = 0; l < K_; ++l) wt[l] = w[l];

    const float4* __restrict__ xcol = (const float4*)(x + (size_t)b * S_ * F_) + f4;
    float4* __restrict__       ocol = (float4*)(out + (size_t)b * S_ * F_) + f4;

    // Window invariant: x[t] lives in win[t % 25].
    // Prefill win[j] = x[clamp(s0 - 25 + j, 0)] for j = 1..24  (t = s0-24 .. s0-1).
    float4 win[K_];
#pragma unroll
    for (int j = 1; j < K_; ++j) {
        int s = s0 - K_ + j;
        s = s < 0 ? 0 : s;
        win[j] = xcol[(size_t)s * F4_];
    }

    for (int i0 = 0; i0 < SEG; i0 += K_) {
#pragma unroll
        for (int u = 0; u < K_; ++u) {
            const int s  = s0 + i0 + u;           // s % 25 == u
            const int sl = s < S_ ? s : (S_ - 1); // clamped load for masked tail
            win[u] = xcol[(size_t)sl * F4_];

            float4 acc;
            acc.x = acc.y = acc.z = acc.w = 0.0f;
#pragma unroll
            for (int l = 0; l < K_; ++l) {
                // offset l corresponds to t = s - 24 + l  -> slot (u + 1 + l) % 25
                const float4 v = win[(u + 1 + l) % K_];
                const float  c = wt[l];
                acc.x += c * v.x;
                acc.y += c * v.y;
                acc.z += c * v.z;
                acc.w += c * v.w;
            }
            if (s < S_) ocol[(size_t)s * F4_] = acc;
        }
    }
}

extern "C" void kernel_launch(void* const* d_in, const int* in_sizes, int n_in,
                              void* d_out, int out_size, void* d_ws, size_t ws_size,
                              hipStream_t stream) {
    const float* x = (const float*)d_in[0];   // [B, S, F] fp32
    const float* w = (const float*)d_in[1];   // [K] fp32
    float* out     = (float*)d_out;           // [B, S, F] fp32

    const int total_threads = B_ * NSEG * F4_;         // 167,936
    const int block = 256;
    const int grid  = (total_threads + block - 1) / block;  // 656
    adapt_smoothing_kernel<<<grid, block, 0, stream>>>(x, w, out);
}